// Round 7
// baseline (210.500 us; speedup 1.0000x reference)
//
#include <hip/hip_runtime.h>
#include <hip/hip_bf16.h>

typedef __attribute__((ext_vector_type(8))) short short8;
typedef __attribute__((ext_vector_type(4))) float f32x4;

#define D_MODEL 512
#define BN 64
#define NPASS 16

__device__ __forceinline__ short f2bf(float f) {
    unsigned u = __builtin_bit_cast(unsigned, f);
    unsigned r = (u + 0x7fffu + ((u >> 16) & 1u)) >> 16;
    return (short)r;
}

__device__ __forceinline__ short4 cvt4(const float4& v) {
    union { __hip_bfloat162 h[2]; short4 s; } u;
    u.h[0] = __float22bfloat162_rn(make_float2(v.x, v.y));
    u.h[1] = __float22bfloat162_rn(make_float2(v.z, v.w));
    return u.s;
}

// Kernel 1: cond[b][k] = ent[s_ent[b]][k] + rel[relation[b]][k]  (bf16 -> ws), a2[b] = ||cond||^2
__global__ void prep_kernel(const int* __restrict__ s_ent, const int* __restrict__ rel,
                            const float* __restrict__ ent, const float* __restrict__ relemb,
                            short* __restrict__ condb, float* __restrict__ a2) {
    const int b = blockIdx.x;
    const int t = threadIdx.x;
    const float4 v = *(const float4*)(ent + (size_t)s_ent[b] * D_MODEL + t * 4);
    const float4 w = *(const float4*)(relemb + (size_t)rel[b] * D_MODEL + t * 4);
    float c0 = v.x + w.x, c1 = v.y + w.y, c2 = v.z + w.z, c3 = v.w + w.w;
    float sq = c0 * c0 + c1 * c1 + c2 * c2 + c3 * c3;

    short4 s;
    s.x = f2bf(c0); s.y = f2bf(c1); s.z = f2bf(c2); s.w = f2bf(c3);
    *(short4*)(condb + (size_t)b * D_MODEL + t * 4) = s;

    #pragma unroll
    for (int off = 1; off < 64; off <<= 1) sq += __shfl_xor(sq, off);
    __shared__ float red[2];
    if ((t & 63) == 0) red[t >> 6] = sq;
    __syncthreads();
    if (t == 0) a2[b] = red[0] + red[1];
}

// Kernel 2: full-K panel blocking. BM=256 (all queries), BN=64 per block, 512 thr = 8 waves.
// Phase 1 (copy): stage the block's ENTIRE B panel (64 rows x 2KB fp32, each row read as
//   contiguous 1KB wave-instructions) via a 16-deep register burst -> cvt once -> swizzled
//   bf16 LDS panel; exact fp32 b2 per row via wave-uniform shfl reduce.
// Phase 2 (compute): BARRIER-FREE K-loop. Wave w owns M rows w*32..w*32+31, all 64 N cols.
//   af from L2-resident condb (2/step), bf from LDS (4 ds_read_b128/step), 8 MFMA/step.
// ent is read exactly once, in >=1KB contiguous granules -> DRAM row-buffer friendly.
__global__ __launch_bounds__(512, 4)
void score_kernel(const float* __restrict__ ent, const short* __restrict__ condb,
                  const float* __restrict__ a2, float* __restrict__ out, const int n_ent) {
    __shared__ __align__(16) short Bp[BN * D_MODEL];   // 64 KB swizzled bf16 panel
    __shared__ float b2s[BN];

    const int tid  = threadIdx.x;
    const int lane = tid & 63;
    const int w    = tid >> 6;                    // 0..7
    const int lrow = lane & 15, g4 = lane >> 4;
    const long long nbase = (long long)blockIdx.x * BN;

    // ---- Phase 1: copy. Pass p: wave w reads row w*8 + (p>>1), half (p&1).
    // Per instruction: 64 lanes x 16B = 1KB contiguous. 16-deep load burst -> max HBM queue.
    const char* gent = (const char*)ent;
    float4 stg[NPASS];
    #pragma unroll
    for (int p = 0; p < NPASS; ++p) {
        const long long grow = min(nbase + w * 8 + (p >> 1), (long long)(n_ent - 1));
        stg[p] = *(const float4*)(gent + grow * 2048 + (p & 1) * 1024 + lane * 16);
    }
    float sqp[8];
    #pragma unroll
    for (int r = 0; r < 8; ++r) sqp[r] = 0.f;
    #pragma unroll
    for (int p = 0; p < NPASS; ++p) {
        const int row = w * 8 + (p >> 1);
        const int cb  = (p & 1) * 512 + lane * 8;          // bf16 row-byte offset [0,1024)
        const float4 v = stg[p];
        sqp[p >> 1] += v.x * v.x + v.y * v.y + v.z * v.z + v.w * v.w;
        // swizzle: XOR row-bits into byte bits 4..6 (keeps 8B chunk intact & aligned)
        *(short4*)((char*)Bp + row * 1024 + (cb ^ ((row & 7) << 4))) = cvt4(v);
    }
    #pragma unroll
    for (int r = 0; r < 8; ++r) {                          // exact fp32 b2 per row
        float s = sqp[r];
        #pragma unroll
        for (int off = 1; off < 64; off <<= 1) s += __shfl_xor(s, off);
        if (lane == 0) b2s[w * 8 + r] = s;
    }
    __syncthreads();   // panel + b2s ready; the ONLY block-wide barrier

    // ---- Phase 2: barrier-free K-loop.
    // A-frag: cond row (w*32 + fm*16 + lrow), k-slice t*32 + g4*8 (16B, L2-resident).
    const short* abase = condb + (size_t)(w * 32 + lrow) * D_MODEL + g4 * 8;

    f32x4 acc[2][4] = {};   // [fm][fn]
    #pragma unroll
    for (int t = 0; t < 16; ++t) {
        const short8 af0 = *(const short8*)(abase + t * 32);
        const short8 af1 = *(const short8*)(abase + t * 32 + 16 * D_MODEL);
        #pragma unroll
        for (int fn = 0; fn < 4; ++fn) {
            const int rb = fn * 16 + lrow;
            const short8 bf = *(const short8*)((const char*)Bp + rb * 1024 +
                                               ((t * 64 + g4 * 16) ^ ((rb & 7) << 4)));
            acc[0][fn] = __builtin_amdgcn_mfma_f32_16x16x32_bf16(af0, bf, acc[0][fn], 0, 0, 0);
            acc[1][fn] = __builtin_amdgcn_mfma_f32_16x16x32_bf16(af1, bf, acc[1][fn], 0, 0, 0);
        }
    }

    // ---- epilogue: d2 = a2[m] - 2*ab + b2[n]; score = -sqrt(max(d2, 1e-12))
    #pragma unroll
    for (int fm = 0; fm < 2; ++fm) {
        const int m0 = w * 32 + fm * 16 + g4 * 4;
        const f32x4 a2v = *(const f32x4*)(a2 + m0);
        #pragma unroll
        for (int fn = 0; fn < 4; ++fn) {
            const long long ng = nbase + fn * 16 + lrow;
            if (ng < n_ent) {
                const float b2v = b2s[fn * 16 + lrow];
                #pragma unroll
                for (int r = 0; r < 4; ++r) {
                    float d2 = a2v[r] - 2.f * acc[fm][fn][r] + b2v;
                    out[(size_t)(m0 + r) * n_ent + ng] = -sqrtf(fmaxf(d2, 1e-12f));
                }
            }
        }
    }
}

extern "C" void kernel_launch(void* const* d_in, const int* in_sizes, int n_in,
                              void* d_out, int out_size, void* d_ws, size_t ws_size,
                              hipStream_t stream) {
    const int*   s_ent  = (const int*)d_in[0];
    const int*   rel    = (const int*)d_in[1];
    // d_in[2] = o_ent, d_in[3] = time : unused by reference forward
    const float* ent    = (const float*)d_in[4];
    const float* relemb = (const float*)d_in[5];
    float* out = (float*)d_out;

    const int bs    = in_sizes[0];              // 256
    const int n_ent = in_sizes[4] / D_MODEL;    // 200000

    short* condb = (short*)d_ws;                               // bs*512 bf16 = 256KB
    float* a2    = (float*)((char*)d_ws + (size_t)bs * D_MODEL * 2);

    prep_kernel<<<bs, 128, 0, stream>>>(s_ent, rel, ent, relemb, condb, a2);

    const int ntiles = (n_ent + BN - 1) / BN;   // 3125
    score_kernel<<<ntiles, 512, 0, stream>>>(ent, condb, a2, out, n_ent);
}